// Round 3
// baseline (1847.391 us; speedup 1.0000x reference)
//
#include <hip/hip_runtime.h>

// dims
#define BB 2
#define SS 1024
#define HH 8
#define DD 64
#define RR 32
#define KK 128
#define ZLEN 1536            // 4K + S
#define ZROW 1152            // staged z positions [K, K+S+K) per (b,r,h,d)
#define HD 512               // H*D
#define HR 256               // H*R
#define SPLIT 8              // d-chunks across blocks
#define DPC 8                // d per chunk  (SPLIT*DPC == DD)

// ---- async global->LDS DMA helpers (wave-wide; LDS dest = uniform base + lane*size) ----
__device__ __forceinline__ void dma16(const float* g, float* l) {
    const int lane = threadIdx.x & 63;
    __builtin_amdgcn_global_load_lds(
        (const __attribute__((address_space(1))) void*)(g + (lane << 2)),
        (__attribute__((address_space(3))) void*)l, 16, 0, 0);
}
__device__ __forceinline__ void dma4(const float* g, float* l) {
    const int lane = threadIdx.x & 63;
    __builtin_amdgcn_global_load_lds(
        (const __attribute__((address_space(1))) void*)(g + lane),
        (__attribute__((address_space(3))) void*)l, 4, 0, 0);
}

// block = (r + 32*dc, h, b); 128 threads (2 waves); thread t computes s = 8t..8t+7
// for d in [dc*8, dc*8+8). Partial sums atomically added to out (zeroed first).
__global__ __launch_bounds__(128, 4) void convspe_kernel(
    const float* __restrict__ q, const float* __restrict__ kmat,
    const float* __restrict__ wq, const float* __restrict__ wk,
    const float* __restrict__ z, float* __restrict__ out)
{
    __shared__ __align__(16) float zbuf[2][ZROW];     // 9.2 KB
    __shared__ __align__(16) float wbuf[2][2 * KK];   // 2 KB (wq row [0..128), wk [128..256))

    const int tid = threadIdx.x;           // 0..127
    const int wave = tid >> 6;
    const int r  = blockIdx.x & 31;
    const int dc = blockIdx.x >> 5;        // 0..7
    const int h = blockIdx.y, b = blockIdx.z;
    const int d0 = dc * DPC;

    const size_t qkbase = (size_t)b * (SS * HD) + (size_t)h * DD;
    const size_t obase  = (size_t)b * (SS * HR) + (size_t)h * RR + (size_t)r;

    // stage z row (1152 f) + both 128-f weight rows for depth d into buffer p (2 waves)
    auto stage = [&](int d, int p) {
        const float* zg  = z  + (size_t)((b * RR + r) * HD + h * DD + d) * ZLEN + KK;
        const float* wqg = wq + (size_t)(h * DD + d) * KK;
        const float* wkg = wk + (size_t)(h * DD + d) * KK;
        if (wave == 0) {
            dma16(zg,       &zbuf[p][0]);
            dma16(zg + 256, &zbuf[p][256]);
            dma4(zg + 1024, &zbuf[p][1024]);
            dma4(wqg,       &wbuf[p][0]);
            dma4(wqg + 64,  &wbuf[p][64]);
        } else {
            dma16(zg + 512, &zbuf[p][512]);
            dma16(zg + 768, &zbuf[p][768]);
            dma4(zg + 1088, &zbuf[p][1088]);
            dma4(wkg,       &wbuf[p][128]);
            dma4(wkg + 64,  &wbuf[p][192]);
        }
    };

    float qacc[8], kacc[8];
    #pragma unroll
    for (int j = 0; j < 8; ++j) { qacc[j] = 0.f; kacc[j] = 0.f; }

    stage(d0, 0);
    __syncthreads();          // vmcnt(0) drained -> buf 0 ready

    #pragma unroll 1
    for (int dp = 0; dp < DPC / 2; ++dp) {
        // q/k scale values for d = d0+2dp, d0+2dp+1 — float2 along contiguous d axis
        float2 qv2[8], kv2[8];
        {
            const size_t qb = qkbase + (size_t)(d0 + 2 * dp);
            #pragma unroll
            for (int j = 0; j < 8; ++j) {
                const size_t g = qb + (size_t)(8 * tid + j) * HD;
                qv2[j] = *(const float2*)&q[g];
                kv2[j] = *(const float2*)&kmat[g];
            }
        }

        #pragma unroll
        for (int dd2 = 0; dd2 < 2; ++dd2) {
            const int dd = 2 * dp + dd2;       // 0..7
            const int p = dd & 1;

            // async prefetch next depth into the other buffer
            if (dd + 1 < DPC) stage(d0 + dd + 1, p ^ 1);

            const float4* Z4  = (const float4*)zbuf[p];
            const float4* WQ4 = (const float4*)&wbuf[p][0];
            const float4* WK4 = (const float4*)&wbuf[p][KK];

            float cq[8], ck[8];
            #pragma unroll
            for (int j = 0; j < 8; ++j) { cq[j] = 0.f; ck[j] = 0.f; }

            float4 za = Z4[2 * tid];           // z[8t .. 8t+3]
            float4 zb = Z4[2 * tid + 1];       // z[8t+4 .. 8t+7]
            #pragma unroll
            for (int c = 0; c < 32; ++c) {
                const float4 zc = Z4[2 * tid + c + 2];   // max idx 287 < 288, in range
                const float4 w_q = WQ4[c];               // uniform -> broadcast
                const float4 w_k = WK4[c];
                float zw[12];
                zw[0] = za.x; zw[1]  = za.y; zw[2]  = za.z; zw[3]  = za.w;
                zw[4] = zb.x; zw[5]  = zb.y; zw[6]  = zb.z; zw[7]  = zb.w;
                zw[8] = zc.x; zw[9]  = zc.y; zw[10] = zc.z; zw[11] = zc.w;
                #pragma unroll
                for (int kj = 0; kj < 4; ++kj) {
                    const float wqv = (kj == 0) ? w_q.x : (kj == 1) ? w_q.y : (kj == 2) ? w_q.z : w_q.w;
                    const float wkv = (kj == 0) ? w_k.x : (kj == 1) ? w_k.y : (kj == 2) ? w_k.z : w_k.w;
                    #pragma unroll
                    for (int j = 0; j < 8; ++j) {
                        cq[j] = fmaf(wkv, zw[kj + j], cq[j]);   // qbar uses wk (the swap)
                        ck[j] = fmaf(wqv, zw[kj + j], ck[j]);   // kbar uses wq
                    }
                }
                za = zb; zb = zc;
            }

            // scale by q/k feature value for this d and accumulate
            #pragma unroll
            for (int j = 0; j < 8; ++j) {
                const float qs = dd2 ? qv2[j].y : qv2[j].x;
                const float ks = dd2 ? kv2[j].y : kv2[j].x;
                qacc[j] = fmaf(qs, cq[j], qacc[j]);
                kacc[j] = fmaf(ks, ck[j], kacc[j]);
            }

            __syncthreads();   // prefetch complete + all reads of buf p done
        }
    }

    // partial-sum epilogue: qhat at [b,s,h,r], khat at +B*S*H*R
    #pragma unroll
    for (int j = 0; j < 8; ++j) {
        const int s = 8 * tid + j;
        unsafeAtomicAdd(&out[obase + (size_t)s * HR], qacc[j]);
        unsafeAtomicAdd(&out[(size_t)(BB * SS * HR) + obase + (size_t)s * HR], kacc[j]);
    }
}

extern "C" void kernel_launch(void* const* d_in, const int* in_sizes, int n_in,
                              void* d_out, int out_size, void* d_ws, size_t ws_size,
                              hipStream_t stream) {
    const float* q  = (const float*)d_in[0];
    const float* k  = (const float*)d_in[1];
    const float* wq = (const float*)d_in[2];
    const float* wk = (const float*)d_in[3];
    const float* z  = (const float*)d_in[4];
    float* out = (float*)d_out;

    hipMemsetAsync(out, 0, (size_t)out_size * sizeof(float), stream);

    dim3 grid(RR * SPLIT, HH, BB);   // 4096 blocks
    dim3 block(128);                  // 2 waves
    hipLaunchKernelGGL(convspe_kernel, grid, block, 0, stream, q, k, wq, wk, z, out);
}

// Round 4
// 540.105 us; speedup vs baseline: 3.4204x; 3.4204x over previous
//
#include <hip/hip_runtime.h>

// dims
#define BB 2
#define SS 1024
#define HH 8
#define DD 64
#define RR 32
#define KK 128
#define ZLEN 1536            // 4K + S
#define ZROW 1152            // staged z positions [K, K+S+K) per (b,r,h,d)
#define HD 512               // H*D
#define HR 256               // H*R
#define SPLIT 4              // d-chunks across blocks
#define DPC 16               // d per chunk  (SPLIT*DPC == DD)
#define PART_PER_OUT (SPLIT * BB * HH * RR * SS)   // 2,097,152 floats (8 MB)

// ---- async global->LDS DMA helpers (wave-wide; LDS dest = uniform base + lane*size) ----
__device__ __forceinline__ void dma16(const float* g, float* l) {
    const int lane = threadIdx.x & 63;
    __builtin_amdgcn_global_load_lds(
        (const __attribute__((address_space(1))) void*)(g + (lane << 2)),
        (__attribute__((address_space(3))) void*)l, 16, 0, 0);
}
__device__ __forceinline__ void dma4(const float* g, float* l) {
    const int lane = threadIdx.x & 63;
    __builtin_amdgcn_global_load_lds(
        (const __attribute__((address_space(1))) void*)(g + lane),
        (__attribute__((address_space(3))) void*)l, 4, 0, 0);
}

// block = (r + 32*dc, h, b); 128 threads (2 waves); thread t computes s = 8t..8t+7
// for d in [dc*16, dc*16+16). Partials (per dc) written coalesced to ws.
__global__ __launch_bounds__(128, 4) void convspe_kernel(
    const float* __restrict__ q, const float* __restrict__ kmat,
    const float* __restrict__ wq, const float* __restrict__ wk,
    const float* __restrict__ z, float* __restrict__ part)
{
    __shared__ __align__(16) float zbuf[2][ZROW];     // 9.2 KB

    const int tid = threadIdx.x;           // 0..127
    const int wave = tid >> 6;
    const int r  = blockIdx.x & 31;
    const int dc = blockIdx.x >> 5;        // 0..SPLIT-1
    const int h = blockIdx.y, b = blockIdx.z;
    const int d0 = dc * DPC;

    const size_t qkbase = (size_t)b * (SS * HD) + (size_t)h * DD;

    // stage z row (1152 f) for depth d into buffer p (split across the 2 waves)
    auto stage = [&](int d, int p) {
        const float* zg = z + (size_t)((b * RR + r) * HD + h * DD + d) * ZLEN + KK;
        if (wave == 0) {
            dma16(zg,       &zbuf[p][0]);
            dma16(zg + 256, &zbuf[p][256]);
            dma4(zg + 1024, &zbuf[p][1024]);
        } else {
            dma16(zg + 512, &zbuf[p][512]);
            dma16(zg + 768, &zbuf[p][768]);
            dma4(zg + 1088, &zbuf[p][1088]);
        }
    };

    float qacc[8], kacc[8];
    #pragma unroll
    for (int j = 0; j < 8; ++j) { qacc[j] = 0.f; kacc[j] = 0.f; }

    stage(d0, 0);
    __syncthreads();          // vmcnt(0) drained -> buf 0 ready

    #pragma unroll 1
    for (int dp = 0; dp < DPC / 2; ++dp) {
        // q/k scale values for d = d0+2dp, d0+2dp+1 — float2 along contiguous d axis
        float2 qv2[8], kv2[8];
        {
            const size_t qb = qkbase + (size_t)(d0 + 2 * dp);
            #pragma unroll
            for (int j = 0; j < 8; ++j) {
                const size_t g = qb + (size_t)(8 * tid + j) * HD;
                qv2[j] = *(const float2*)&q[g];
                kv2[j] = *(const float2*)&kmat[g];
            }
        }

        #pragma unroll
        for (int dd2 = 0; dd2 < 2; ++dd2) {
            const int dd = 2 * dp + dd2;       // 0..DPC-1
            const int d  = d0 + dd;
            const int p  = dd & 1;

            // async prefetch next depth into the other buffer
            if (dd + 1 < DPC) stage(d + 1, p ^ 1);

            // block-uniform weight rows -> scalar (SMEM) loads, no LDS
            const float* __restrict__ wqg = wq + (size_t)(h * DD + d) * KK;
            const float* __restrict__ wkg = wk + (size_t)(h * DD + d) * KK;

            const float4* Z4 = (const float4*)zbuf[p];

            float cq[8], ck[8];
            #pragma unroll
            for (int j = 0; j < 8; ++j) { cq[j] = 0.f; ck[j] = 0.f; }

            float4 za = Z4[2 * tid];           // z idx 8t .. 8t+3
            float4 zb = Z4[2 * tid + 1];       // z idx 8t+4 .. 8t+7
            #pragma unroll
            for (int c = 0; c < 32; ++c) {
                const float4 zc = Z4[2 * tid + c + 2];   // max idx 287 < 288
                const float4 w_q = *(const float4*)&wqg[4 * c];   // uniform -> s_load
                const float4 w_k = *(const float4*)&wkg[4 * c];
                float zw[12];
                zw[0] = za.x; zw[1]  = za.y; zw[2]  = za.z; zw[3]  = za.w;
                zw[4] = zb.x; zw[5]  = zb.y; zw[6]  = zb.z; zw[7]  = zb.w;
                zw[8] = zc.x; zw[9]  = zc.y; zw[10] = zc.z; zw[11] = zc.w;
                #pragma unroll
                for (int kj = 0; kj < 4; ++kj) {
                    const float wqv = (kj == 0) ? w_q.x : (kj == 1) ? w_q.y : (kj == 2) ? w_q.z : w_q.w;
                    const float wkv = (kj == 0) ? w_k.x : (kj == 1) ? w_k.y : (kj == 2) ? w_k.z : w_k.w;
                    #pragma unroll
                    for (int j = 0; j < 8; ++j) {
                        cq[j] = fmaf(wkv, zw[kj + j], cq[j]);   // qbar uses wk (the swap)
                        ck[j] = fmaf(wqv, zw[kj + j], ck[j]);   // kbar uses wq
                    }
                }
                za = zb; zb = zc;
            }

            // scale by q/k feature value for this d and accumulate
            #pragma unroll
            for (int j = 0; j < 8; ++j) {
                const float qs = dd2 ? qv2[j].y : qv2[j].x;
                const float ks = dd2 ? kv2[j].y : kv2[j].x;
                qacc[j] = fmaf(qs, cq[j], qacc[j]);
                kacc[j] = fmaf(ks, ck[j], kacc[j]);
            }

            __syncthreads();   // prefetch complete + all reads of buf p done
        }
    }

    // coalesced partial store: part[out][dc][b][h][r][s], thread owns s = 8t..8t+7
    {
        float* pq = part + ((((size_t)dc * BB + b) * HH + h) * RR + r) * SS + 8 * tid;
        float* pk = pq + PART_PER_OUT;
        *(float4*)&pq[0] = make_float4(qacc[0], qacc[1], qacc[2], qacc[3]);
        *(float4*)&pq[4] = make_float4(qacc[4], qacc[5], qacc[6], qacc[7]);
        *(float4*)&pk[0] = make_float4(kacc[0], kacc[1], kacc[2], kacc[3]);
        *(float4*)&pk[4] = make_float4(kacc[4], kacc[5], kacc[6], kacc[7]);
    }
}

// reduce over dc + transpose: part[out][dc][b][h][r][s] -> out[out][b][s][h][r]
// block = (out_sel + 2*sc, h, b), 256 threads, s-chunk of 256
__global__ __launch_bounds__(256) void reduce_kernel(
    const float* __restrict__ part, float* __restrict__ out)
{
    __shared__ float tile[RR][257];

    const int tid = threadIdx.x;
    const int out_sel = blockIdx.x & 1;
    const int sc = blockIdx.x >> 1;        // 0..3
    const int h = blockIdx.y, b = blockIdx.z;
    const int s0 = sc * 256;

    const size_t pbase = (size_t)out_sel * PART_PER_OUT;
    #pragma unroll 1
    for (int r = 0; r < RR; ++r) {
        const size_t base = pbase + (((size_t)b * HH + h) * RR + r) * SS + s0 + tid;
        float sum = 0.f;
        #pragma unroll
        for (int dcq = 0; dcq < SPLIT; ++dcq)
            sum += part[base + (size_t)dcq * (BB * HH * RR * SS)];
        tile[r][tid] = sum;
    }
    __syncthreads();

    const int r = tid & 31;
    const int so = tid >> 5;               // 0..7
    const size_t obase = (size_t)out_sel * (BB * SS * HR)
                       + ((size_t)b * SS) * HR + (size_t)h * RR + r;
    #pragma unroll
    for (int i = 0; i < 32; ++i) {
        const int sl = i * 8 + so;
        out[obase + (size_t)(s0 + sl) * HR] = tile[r][sl];
    }
}

extern "C" void kernel_launch(void* const* d_in, const int* in_sizes, int n_in,
                              void* d_out, int out_size, void* d_ws, size_t ws_size,
                              hipStream_t stream) {
    const float* q  = (const float*)d_in[0];
    const float* k  = (const float*)d_in[1];
    const float* wq = (const float*)d_in[2];
    const float* wk = (const float*)d_in[3];
    const float* z  = (const float*)d_in[4];
    float* out  = (float*)d_out;
    float* part = (float*)d_ws;            // needs 2*PART_PER_OUT*4 = 16.8 MB

    dim3 grid(RR * SPLIT, HH, BB);         // 2048 blocks
    dim3 block(128);                       // 2 waves
    hipLaunchKernelGGL(convspe_kernel, grid, block, 0, stream, q, k, wq, wk, z, part);

    dim3 rgrid(2 * (SS / 256), HH, BB);    // 128 blocks
    dim3 rblock(256);
    hipLaunchKernelGGL(reduce_kernel, rgrid, rblock, 0, stream, part, out);
}

// Round 6
// 321.911 us; speedup vs baseline: 5.7388x; 1.6778x over previous
//
#include <hip/hip_runtime.h>

// dims
#define BB 2
#define SS 1024
#define HH 8
#define DD 64
#define RR 32
#define KK 128
#define ZLEN 1536
#define HD 512

// tiling
#define MS 256            // s per block (4 stiles)
#define DC 16             // d per block (4 dc chunks)
#define NTC 24            // t-chunks of 16 (window = 256+128 = 384)
#define WROWS 192         // tau in [-32,160), zero-padded outside [0,128)
#define WSEG (WROWS*DC)   // 3072 halves = 6 KB per (h,dc) per array
#define PARTS_FLOATS (256*8*2*64*16)   // 4,194,304 f32 = 16 MiB

typedef _Float16 f16x8 __attribute__((ext_vector_type(8)));
typedef _Float16 f16x2 __attribute__((ext_vector_type(2)));
typedef float    f32x16 __attribute__((ext_vector_type(16)));

__device__ __forceinline__ void dma16h(const _Float16* g, _Float16* l) {
    const int lane = threadIdx.x & 63;
    __builtin_amdgcn_global_load_lds(
        (const __attribute__((address_space(1))) void*)(g + lane * 8),
        (__attribute__((address_space(3))) void*)l, 16, 0, 0);
}

// ---- w prep: w[(h*64+dc*16+di)][k] f32 -> wG[h][dc][ti=tau+32][di] f16, zero outside band ----
__global__ __launch_bounds__(256) void wprep_kernel(
    const float* __restrict__ wq, const float* __restrict__ wk,
    _Float16* __restrict__ wqG, _Float16* __restrict__ wkG)
{
    const int tid = threadIdx.x;
    const int h = blockIdx.x & 7, dc = blockIdx.x >> 3;   // grid 32
    #pragma unroll
    for (int i = 0; i < 12; ++i) {
        const int idx = i * 256 + tid;                    // 0..3071
        const int ti = idx >> 4, di = idx & 15;
        const int tau = ti - 32;
        float vq = 0.f, vk = 0.f;
        if (tau >= 0 && tau < KK) {
            const int src = (h * 64 + dc * 16 + di) * KK + tau;
            vq = wq[src]; vk = wk[src];
        }
        const int dst = (h * 4 + dc) * WSEG + idx;
        wqG[dst] = (_Float16)vq; wkG[dst] = (_Float16)vk;
    }
}

// ---- main: C[r][s] = sum_{t,d} z[r,d,t] * (w[d,t-s]*qk[s,d]), MFMA 32x32x16 f16 ----
// block = (b,h,stile,dc), 512 thr (8 waves = 8 s-subtiles of 32). Partials to ws.
__global__ __launch_bounds__(512) void convspe_mfma(
    const float* __restrict__ q, const float* __restrict__ kmat,
    const _Float16* __restrict__ wqG, const _Float16* __restrict__ wkG,
    const float* __restrict__ z, float* __restrict__ parts)
{
    __shared__ __align__(16) _Float16 zbuf[2][16 * 32 * 16];   // [ts][r][d] 16KB x2
    __shared__ __align__(16) _Float16 wqs[WSEG];
    __shared__ __align__(16) _Float16 wks[WSEG];

    const int tid  = threadIdx.x;
    const int wave = tid >> 6;          // = s-subtile
    const int lane = tid & 63;
    const int rl   = lane & 31;
    const int hi   = lane >> 5;

    const int bx = blockIdx.x;
    const int dc = bx & 3, stile = (bx >> 2) & 3, h = (bx >> 4) & 7, b = bx >> 7;
    const int s0b = stile * MS;
    const int d0  = dc * DC;

    // stage w tiles (LDS layout = linear [ti][di], DMA-compatible)
    if (wave == 0) {
        const _Float16* seg = wqG + (h * 4 + dc) * WSEG;
        #pragma unroll
        for (int i = 0; i < 6; ++i) dma16h(seg + i * 512, wqs + i * 512);
    } else if (wave == 1) {
        const _Float16* seg = wkG + (h * 4 + dc) * WSEG;
        #pragma unroll
        for (int i = 0; i < 6; ++i) dma16h(seg + i * 512, wks + i * 512);
    }

    // per-lane q/k fragments: q[s][d0+8*hi+j], j=0..7  (B-operand k-layout)
    f16x8 qf, kf;
    {
        const int s = s0b + wave * 32 + rl;
        const size_t base = (((size_t)b * SS + s) * HH + h) * DD + d0 + 8 * hi;
        #pragma unroll
        for (int j = 0; j < 8; ++j) {
            qf[j] = (_Float16)q[base + j];
            kf[j] = (_Float16)kmat[base + j];
        }
    }

    // z staging: thread = (r, th, dp): rows d = d0+2dp, d0+2dp+1; t-half th*8..+8
    const int sr  = tid >> 4;            // 0..31
    const int sth = (tid >> 3) & 1;      // 0..1
    const int sdp = tid & 7;             // 0..7
    const float* zr0 = z + ((size_t)(b * RR + sr) * HD + h * DD + d0 + 2 * sdp) * ZLEN
                         + KK + s0b + sth * 8;
    const float* zr1 = zr0 + ZLEN;

    float4 ra[2], rb[2];
    auto loadchunk = [&](int tc) {
        const float4* p0 = (const float4*)(zr0 + tc * 16);
        const float4* p1 = (const float4*)(zr1 + tc * 16);
        #pragma unroll
        for (int i = 0; i < 2; ++i) { ra[i] = p0[i]; rb[i] = p1[i]; }
    };
    auto writechunk = [&](int p) {
        f16x2* dst = (f16x2*)zbuf[p];
        #pragma unroll
        for (int i = 0; i < 2; ++i) {
            const float av[4] = {ra[i].x, ra[i].y, ra[i].z, ra[i].w};
            const float bv[4] = {rb[i].x, rb[i].y, rb[i].z, rb[i].w};
            #pragma unroll
            for (int e = 0; e < 4; ++e) {
                const int ts = sth * 8 + i * 4 + e;
                dst[(ts * 32 + sr) * 8 + sdp] =
                    __builtin_bit_cast(f16x2, __builtin_amdgcn_cvt_pkrtz(av[e], bv[e]));
            }
        }
    };

    f32x16 accq, acck;
    #pragma unroll
    for (int j = 0; j < 16; ++j) { accq[j] = 0.f; acck[j] = 0.f; }

    loadchunk(0);
    writechunk(0);
    loadchunk(1);
    __syncthreads();     // zbuf0 ready; barrier drains w-DMA too

    for (int tc = 0; tc < NTC; ++tc) {
        const int p = tc & 1;
        const int tqbase = tc * 16 - wave * 32;      // tau_s = tqbase + ts
        #pragma unroll 1
        for (int ts = 0; ts < 16; ++ts) {
            const int tau_s = tqbase + ts;           // wave-uniform
            if (tau_s < 0 || tau_s >= 160) continue;
            const f16x8 a = *(const f16x8*)&zbuf[p][(ts * 32 + rl) * 16 + 8 * hi];
            const int row = tau_s - rl + 32;         // in [1,191]
            const f16x8 wkf = *(const f16x8*)&wks[row * 16 + 8 * hi];
            const f16x8 wqf = *(const f16x8*)&wqs[row * 16 + 8 * hi];
            accq = __builtin_amdgcn_mfma_f32_32x32x16_f16(a, wkf * qf, accq, 0, 0, 0); // qbar uses wk
            acck = __builtin_amdgcn_mfma_f32_32x32x16_f16(a, wqf * kf, acck, 0, 0, 0); // kbar uses wq
        }
        if (tc + 1 < NTC) writechunk((tc + 1) & 1);
        if (tc + 2 < NTC) loadchunk(tc + 2);
        __syncthreads();
    }

    // partials: parts[bx][sub][o][lane][reg]  (fully coalesced 64B/lane)
    {
        float* pq = parts + ((((size_t)bx * 8 + wave) * 2 + 0) * 64 + lane) * 16;
        float* pk = parts + ((((size_t)bx * 8 + wave) * 2 + 1) * 64 + lane) * 16;
        #pragma unroll
        for (int g = 0; g < 4; ++g) {
            *(float4*)&pq[g * 4] = make_float4(accq[4*g], accq[4*g+1], accq[4*g+2], accq[4*g+3]);
            *(float4*)&pk[g * 4] = make_float4(acck[4*g], acck[4*g+1], acck[4*g+2], acck[4*g+3]);
        }
    }
}

// ---- reduce over dc: out[o][b][s][h][r], thread = one r-quad (coalesced float4 out) ----
__global__ __launch_bounds__(256) void reduce_kernel(
    const float* __restrict__ parts, float* __restrict__ out)
{
    const int idx = blockIdx.x * 256 + threadIdx.x;   // 0..262143
    const int rq = idx & 7, h = (idx >> 3) & 7, s = (idx >> 6) & 1023;
    const int b = (idx >> 16) & 1, o = idx >> 17;
    const int stile = s >> 8, sub = (s >> 5) & 7, rl = s & 31;

    float acc4[4] = {0.f, 0.f, 0.f, 0.f};
    #pragma unroll
    for (int dc = 0; dc < 4; ++dc) {
        const int bx = ((b * 8 + h) * 4 + stile) * 4 + dc;
        const float* pb = parts + (((size_t)bx * 8 + sub) * 2 + o) * 1024;
        #pragma unroll
        for (int i = 0; i < 4; ++i) {
            const int r = rq * 4 + i;
            const int hi2 = (r >> 2) & 1;
            const int reg = (r & 3) + 4 * (r >> 3);   // C/D: row=(reg&3)+8*(reg>>2)+4*hi
            acc4[i] += pb[(hi2 * 32 + rl) * 16 + reg];
        }
    }
    *(float4*)&out[(size_t)idx * 4] = make_float4(acc4[0], acc4[1], acc4[2], acc4[3]);
}

extern "C" void kernel_launch(void* const* d_in, const int* in_sizes, int n_in,
                              void* d_out, int out_size, void* d_ws, size_t ws_size,
                              hipStream_t stream) {
    const float* q  = (const float*)d_in[0];
    const float* k  = (const float*)d_in[1];
    const float* wq = (const float*)d_in[2];
    const float* wk = (const float*)d_in[3];
    const float* z  = (const float*)d_in[4];
    float* out = (float*)d_out;

    float* parts   = (float*)d_ws;                               // 16 MiB
    _Float16* wqG  = (_Float16*)((char*)d_ws + (size_t)PARTS_FLOATS * 4);
    _Float16* wkG  = wqG + 8 * 4 * WSEG;                         // 192 KiB each

    hipLaunchKernelGGL(wprep_kernel, dim3(32), dim3(256), 0, stream, wq, wk, wqG, wkG);
    hipLaunchKernelGGL(convspe_mfma, dim3(256), dim3(512), 0, stream,
                       q, k, wqG, wkG, z, parts);
    hipLaunchKernelGGL(reduce_kernel, dim3(1024), dim3(256), 0, stream, parts, out);
}